// Round 7
// baseline (155.549 us; speedup 1.0000x reference)
//
#include <hip/hip_runtime.h>

#define NPTS  65536
#define KNB   32
#define KPn   15
#define CIN   64
#define COUT  128
#define MPTS  32            // points per block (2 MFMA M-tiles)
#define THREADS 512
#define WSTRIDE 968         // wl row stride in bf16 elements (960 + 8 pad)
#define BCAP  32            // per-point active-entry bucket capacity (λ≈2)
#define NTILE 8             // 128 cols / 16
#define KSTEPS 30           // 960 / 32

typedef __attribute__((ext_vector_type(8))) short short8;
typedef __attribute__((ext_vector_type(4))) float f32x4;

__device__ __forceinline__ unsigned int f2bf(float f) {
    union { float f; unsigned int i; } v; v.f = f;
    return (v.i + 0x7fffu + ((v.i >> 16) & 1u)) >> 16;   // RNE
}

// ---- prep: pack weights into MFMA B-fragment order with permuted K ----
// flat K position f = ks*32 + q*8 + j maps to original row kpk*64 + cg*8 + cw
// where cg = f/120, rem = f%120, kpk = rem/8, cw = rem&7.
__global__ void wtrans_kernel(const float* __restrict__ w,
                              unsigned short* __restrict__ wTf) {
    const int d = blockIdx.x * 256 + threadIdx.x;
    if (d < NTILE * KSTEPS * 64 * 8) {
        const int j    = d & 7;
        const int lane = (d >> 3) & 63;
        const int ks   = (d >> 9) % KSTEPS;
        const int t    = d / (KSTEPS * 512);
        const int f    = ks * 32 + (lane >> 4) * 8 + j;
        const int cg   = f / 120;
        const int rem  = f - cg * 120;
        const int kpk  = rem >> 3;
        const int cw   = rem & 7;
        const int orig = kpk * 64 + cg * 8 + cw;     // row in W[960][128]
        const int n    = t * 16 + (lane & 15);
        wTf[d] = (unsigned short)f2bf(w[(size_t)orig * COUT + n]);
    }
}

__global__ __launch_bounds__(THREADS, 4) void kpconv_kernel(
    const float* __restrict__ pos,         // [N,3] f32
    const float* __restrict__ feats,       // [N,64] f32
    const float* __restrict__ kpts,        // [15,3] f32
    const unsigned short* __restrict__ wTf,// fragment-packed bf16 weights
    const int*   __restrict__ neighbors,   // [N,32] int32
    float*       __restrict__ out)         // [N,128] f32
{
    __shared__ unsigned short wl[MPTS * WSTRIDE]; // 61952 B bf16 (permuted-K)
    __shared__ int   bcnt[MPTS];
    __shared__ int   bid[MPTS][BCAP];             // (nb << 4) | k
    __shared__ float bval[MPTS][BCAP];
    __shared__ float cposf[MPTS * 3];
    __shared__ float4 kpq[KPn];                   // {x, y, z, |kp|^2}
    __shared__ float R2s;                         // (0.1 + max|kp|)^2

    const int tid = threadIdx.x;
    const int n0  = blockIdx.x * MPTS;

    // ---- init ----
    if (tid < MPTS) bcnt[tid] = 0;
    if (tid < MPTS * 3) cposf[tid] = pos[(size_t)n0 * 3 + tid];
    if (tid < KPn) {
        const float x = kpts[tid * 3 + 0];
        const float y = kpts[tid * 3 + 1];
        const float z = kpts[tid * 3 + 2];
        kpq[tid] = make_float4(x, y, z, x * x + y * y + z * z);
    }
    if (tid == THREADS - 1) {                     // doesn't collide with kpq writers
        float mx = 0.f;
        for (int k = 0; k < KPn; ++k) {
            const float x = kpts[k * 3 + 0];
            const float y = kpts[k * 3 + 1];
            const float z = kpts[k * 3 + 2];
            mx = fmaxf(mx, x * x + y * y + z * z);
        }
        const float R = 0.1f + sqrtf(mx);
        R2s = R * R;
    }
    __syncthreads();

    // ---- stage 1a: pruned influence scan over 1024 (p,j) slots ----
    {
        const float R2 = R2s;
        #pragma unroll
        for (int it = 0; it < MPTS * KNB / THREADS; ++it) {
            const int s  = tid + it * THREADS;
            const int p  = s >> 5;
            const int nb = neighbors[(size_t)n0 * KNB + s];
            const float rx = pos[(size_t)nb * 3 + 0] - cposf[p * 3 + 0];
            const float ry = pos[(size_t)nb * 3 + 1] - cposf[p * 3 + 1];
            const float rz = pos[(size_t)nb * 3 + 2] - cposf[p * 3 + 2];
            const float d2r = rx * rx + ry * ry + rz * rz;
            if (d2r < R2) {                      // ~6% of slots survive
                const float hd = 0.5f * (d2r - 0.01f);
                #pragma unroll
                for (int k = 0; k < KPn; ++k) {
                    const float4 kp = kpq[k];
                    const float dot = rx * kp.x + ry * kp.y + rz * kp.z;
                    // |r-kp|^2 < 0.01  <=>  dot > (d2r + |kp|^2 - 0.01)/2
                    if (dot > hd + 0.5f * kp.w) {
                        const float d2 = fmaxf(d2r - 2.f * dot + kp.w, 0.f);
                        const float w = 1.0f - 10.0f * sqrtf(d2);
                        const int idx = atomicAdd(&bcnt[p], 1);
                        if (idx < BCAP) { bid[p][idx] = (nb << 4) | k; bval[p][idx] = w; }
                    }
                }
            }
        }
    }
    __syncthreads();

    // ---- stage 1b: ownership accumulation, 8 channels per work item ----
    // work item wi = p*128 + k*8 + cg (k==15 hole); all acc statically indexed
    #pragma unroll
    for (int it = 0; it < 8; ++it) {
        const int wi = tid + it * THREADS;           // 0..4095
        const int cg = wi & 7;
        const int k  = (wi >> 3) & 15;
        const int p  = wi >> 7;                      // 0..31
        if (k < KPn) {
            float a0=0.f,a1=0.f,a2=0.f,a3=0.f,a4=0.f,a5=0.f,a6=0.f,a7=0.f;
            const int cnt = min(bcnt[p], BCAP);
            for (int e = 0; e < cnt; ++e) {
                const int id = bid[p][e];
                if ((id & 15) == k) {
                    const float wv = bval[p][e];
                    const float* fr = feats + (size_t)(id >> 4) * CIN + cg * 8;
                    const float4 f0 = *(const float4*)fr;
                    const float4 f1 = *(const float4*)(fr + 4);
                    a0 += wv * f0.x; a1 += wv * f0.y; a2 += wv * f0.z; a3 += wv * f0.w;
                    a4 += wv * f1.x; a5 += wv * f1.y; a6 += wv * f1.z; a7 += wv * f1.w;
                }
            }
            uint4 u;
            u.x = f2bf(a0) | (f2bf(a1) << 16);
            u.y = f2bf(a2) | (f2bf(a3) << 16);
            u.z = f2bf(a4) | (f2bf(a5) << 16);
            u.w = f2bf(a6) | (f2bf(a7) << 16);
            *(uint4*)(wl + p * WSTRIDE + cg * 120 + k * 8) = u;   // permuted-K
        }
    }
    __syncthreads();

    // ---- stage 2: out[32][128] = wl @ W via MFMA bf16 ----
    // wave w owns N-tile w; B loaded once per ks, reused for both M-tiles.
    {
        const int wave = tid >> 6;
        const int lane = tid & 63;
        const int m    = lane & 15;
        const int q    = lane >> 4;

        f32x4 acc0 = {0.f, 0.f, 0.f, 0.f};   // points 0..15
        f32x4 acc1 = {0.f, 0.f, 0.f, 0.f};   // points 16..31

        const unsigned short* a0p = wl + m * WSTRIDE + q * 8;
        const unsigned short* a1p = a0p + 16 * WSTRIDE;
        const short8* bp = (const short8*)wTf + (size_t)wave * KSTEPS * 64 + lane;

        #pragma unroll 3
        for (int ks = 0; ks < KSTEPS; ++ks, a0p += 32, a1p += 32) {
            const short8 a0 = *(const short8*)a0p;
            const short8 a1 = *(const short8*)a1p;
            const short8 b  = bp[ks * 64];
            acc0 = __builtin_amdgcn_mfma_f32_16x16x32_bf16(a0, b, acc0, 0, 0, 0);
            acc1 = __builtin_amdgcn_mfma_f32_16x16x32_bf16(a1, b, acc1, 0, 0, 0);
        }

        // C/D layout: col = lane&15, row = q*4 + reg
        const int c = wave * 16 + m;
        #pragma unroll
        for (int r = 0; r < 4; ++r) {
            out[(size_t)(n0 + q * 4 + r) * COUT + c]      = acc0[r];
            out[(size_t)(n0 + 16 + q * 4 + r) * COUT + c] = acc1[r];
        }
    }
}

extern "C" void kernel_launch(void* const* d_in, const int* in_sizes, int n_in,
                              void* d_out, int out_size, void* d_ws, size_t ws_size,
                              hipStream_t stream) {
    const float* pos       = (const float*)d_in[0];
    const float* feats     = (const float*)d_in[1];
    const float* kpts      = (const float*)d_in[2];
    const float* weights   = (const float*)d_in[3];
    const int*   neighbors = (const int*)d_in[4];
    float*       out       = (float*)d_out;
    unsigned short* wTf    = (unsigned short*)d_ws;   // 245760 B

    wtrans_kernel<<<(NTILE * KSTEPS * 512 + 255) / 256, 256, 0, stream>>>(weights, wTf);
    kpconv_kernel<<<NPTS / MPTS, THREADS, 0, stream>>>(pos, feats, kpts, wTf, neighbors, out);
}